// Round 9
// baseline (312.965 us; speedup 1.0000x reference)
//
#include <hip/hip_runtime.h>
#include <math.h>
#include <stdint.h>

// x (32,32,32,512) fp32, W (512,512) fp32. b=32, n=1024, d=512, emb=512, lambda=1.
// pooled = (P^T P + I)^-1 (P^T 1)  [push-through identity]
// Round 9: split-CG — 8 blocks per batch (grid 256 = every CU), each owns a
// 64-col slice of G (64KB, L2-resident). One device-scope flag sync per iter
// (y-slice + p.y partial publish, counter spin, parity double-buffer). All
// blocks keep full p,r,x redundantly -> bit-identical, deterministic.
// NITER back to 14 (anchor: absmax 1.83e-3, 1.8x margin).

#define B    32
#define NPTS 1024
#define D    512
#define EMB  512
#define NITER 14
#define SLICES 8
#define SW   64

typedef __attribute__((ext_vector_type(8))) short short8;
typedef __attribute__((ext_vector_type(4))) float f32x4;
typedef __attribute__((ext_vector_type(8))) _Float16 h16x8;
typedef __attribute__((ext_vector_type(4))) _Float16 h16x4;

#define MFMA16F(a, b, c) __builtin_amdgcn_mfma_f32_16x16x32_f16(a, b, c, 0, 0, 0)

__device__ __forceinline__ void gload16(const void* g, void* lds_wave_base) {
    __builtin_amdgcn_global_load_lds(
        (const __attribute__((address_space(1))) void*)g,
        (__attribute__((address_space(3))) void*)lds_wave_base, 16, 0, 0);
}

// ---------------------------------------------------------------- prep: x(b,n,d) -> Q (b,d,n) fp16 + colsum partials
__global__ __launch_bounds__(256) void prep_kernel(const float* __restrict__ x,
                                                   short* __restrict__ Qh,
                                                   float* __restrict__ psum,
                                                   int b0) {
    int n0 = blockIdx.x * 64, d0 = blockIdx.y * 64, bl = blockIdx.z;
    const float* xb = x + (size_t)bl * NPTS * D;
    __shared__ float tile[64][65];
    __shared__ float cs[4][64];
    int t = threadIdx.x;
    int lrow = t >> 4, lc4 = (t & 15) * 4;
    #pragma unroll
    for (int r = 0; r < 4; ++r) {
        int row = lrow + r * 16;
        const float* src = xb + (size_t)(n0 + row) * D + d0 + lc4;
        tile[row][lc4 + 0] = src[0];
        tile[row][lc4 + 1] = src[1];
        tile[row][lc4 + 2] = src[2];
        tile[row][lc4 + 3] = src[3];
    }
    __syncthreads();

    {   // column partial sums (colsum fusion)
        int col = t & 63, grp = t >> 6;
        float s = 0.f;
        #pragma unroll
        for (int r = 0; r < 16; ++r) s += tile[grp * 16 + r][col];
        cs[grp][col] = s;
    }
    __syncthreads();
    if (t < 64)
        psum[((size_t)(b0 + bl) * 16 + blockIdx.x) * D + d0 + t] =
            cs[0][t] + cs[1][t] + cs[2][t] + cs[3][t];

    // transposed fp16 pack
    int drow = t >> 2, nseg = (t & 3) * 16;
    size_t obase = (size_t)bl * D * NPTS + (size_t)(d0 + drow) * NPTS + n0 + nseg;
    short8 h0, h1;
    #pragma unroll
    for (int k = 0; k < 8; ++k) {
        _Float16 hv = (_Float16)tile[nseg + k][drow];
        h0[k] = __builtin_bit_cast(short, hv);
    }
    #pragma unroll
    for (int k = 0; k < 8; ++k) {
        _Float16 hv = (_Float16)tile[nseg + 8 + k][drow];
        h1[k] = __builtin_bit_cast(short, hv);
    }
    *(short8*)(Qh + obase)     = h0;
    *(short8*)(Qh + obase + 8) = h1;
}

// ---------------------------------------------------------------- syrk: G = Q Q^T (fp16 MFMA), BK=64, XOR-swizzled LDS
__global__ __launch_bounds__(256) void syrk_kernel(const short* __restrict__ Qh,
                                                   _Float16* __restrict__ G) {
    int bx = blockIdx.x, bl = blockIdx.y;
    int i = 0, rem = bx;
    #pragma unroll
    for (int ii = 0; ii < 4; ++ii) {
        int c = 4 - ii;
        if (rem < c) { i = ii; break; }
        rem -= c;
    }
    int j = i + rem;
    int i0 = i * 128, j0 = j * 128;

    const short* Qhb = Qh + (size_t)bl * D * NPTS;
    _Float16* Gb = G + (size_t)bl * D * D;

    __shared__ short smem[2 * 128 * 64];   // A, B: [128][64] fp16 (16 KB each)
    char* smb = (char*)smem;

    int t = threadIdx.x;
    int lane = t & 63, wid = t >> 6;
    int wm = wid >> 1, wn = wid & 1;
    int mrow = lane & 15;
    int kq = lane >> 4;

    f32x4 acc[4][4];
    f32x4 zero = {0.f, 0.f, 0.f, 0.f};
    #pragma unroll
    for (int a = 0; a < 4; ++a)
        #pragma unroll
        for (int c = 0; c < 4; ++c) acc[a][c] = zero;

    for (int kt = 0; kt < NPTS / 64; ++kt) {
        int ks = kt * 64;
        #pragma unroll
        for (int p = 0; p < 4; ++p) {
            int off = p * 4096 + t * 16;            // linear byte offset in 16KB tile
            int row = off >> 7, inb = off & 127;
            int sinb = inb ^ ((row & 7) << 4);      // pre-swizzled global source
            int ldsoff = p * 4096 + wid * 1024;     // wave-uniform linear dest
            const char* sA = (const char*)(Qhb + (size_t)(i0 + row) * NPTS + ks) + sinb;
            const char* sB = (const char*)(Qhb + (size_t)(j0 + row) * NPTS + ks) + sinb;
            gload16(sA, smb + ldsoff);
            gload16(sB, smb + 16384 + ldsoff);
        }
        __syncthreads();

        short8 ah[2][4], bh[2][4];
        #pragma unroll
        for (int h = 0; h < 2; ++h)
            #pragma unroll
            for (int f = 0; f < 4; ++f) {
                int ra = wm * 64 + f * 16 + mrow;
                int rb = wn * 64 + f * 16 + mrow;
                int ca = (h * 4 + kq) ^ (ra & 7);
                int cb = (h * 4 + kq) ^ (rb & 7);
                ah[h][f] = *(const short8*)(smb + ra * 128 + ca * 16);
                bh[h][f] = *(const short8*)(smb + 16384 + rb * 128 + cb * 16);
            }
        #pragma unroll
        for (int h = 0; h < 2; ++h)
            #pragma unroll
            for (int fm = 0; fm < 4; ++fm)
                #pragma unroll
                for (int fn = 0; fn < 4; ++fn)
                    acc[fm][fn] = MFMA16F(__builtin_bit_cast(h16x8, ah[h][fm]),
                                          __builtin_bit_cast(h16x8, bh[h][fn]),
                                          acc[fm][fn]);
        __syncthreads();
    }

    int crow0 = i0 + wm * 64 + (lane >> 4) * 4;
    int ccol0 = j0 + wn * 64 + mrow;
    #pragma unroll
    for (int fm = 0; fm < 4; ++fm)
        #pragma unroll
        for (int fn = 0; fn < 4; ++fn)
            #pragma unroll
            for (int r = 0; r < 4; ++r)
                Gb[(size_t)(crow0 + fm * 16 + r) * D + (ccol0 + fn * 16)] =
                    (_Float16)acc[fm][fn][r];
    if (i != j) {
        #pragma unroll
        for (int fm = 0; fm < 4; ++fm)
            #pragma unroll
            for (int fn = 0; fn < 4; ++fn) {
                h16x4 v = {(_Float16)acc[fm][fn][0], (_Float16)acc[fm][fn][1],
                           (_Float16)acc[fm][fn][2], (_Float16)acc[fm][fn][3]};
                *(h16x4*)&Gb[(size_t)(ccol0 + fn * 16) * D + (crow0 + fm * 16)] = v;
            }
    }
}

// ---------------------------------------------------------------- split-CG
__device__ __forceinline__ float block_reduce(float v, float* red, int nwaves) {
    #pragma unroll
    for (int o = 32; o > 0; o >>= 1) v += __shfl_down(v, o);
    int wid = threadIdx.x >> 6, lane = threadIdx.x & 63;
    __syncthreads();
    if (lane == 0) red[wid] = v;
    __syncthreads();
    float s = 0.f;
    if ((int)threadIdx.x < nwaves) {
        s = red[threadIdx.x];
        #pragma unroll
        for (int o = 8; o > 0; o >>= 1) s += __shfl_down(s, o);
    }
    return s;   // valid in thread 0
}

__global__ __launch_bounds__(512) void cg_split_kernel(const _Float16* __restrict__ G,
                                                       const float* __restrict__ psum,
                                                       float* __restrict__ pooled,
                                                       float* __restrict__ ybuf,
                                                       float* __restrict__ pybuf,
                                                       int* __restrict__ cnt) {
    int bid = blockIdx.x;
    int b = bid & 31, sl = bid >> 5;          // slices of one batch share bid%32 -> same XCD under round-robin
    const _Float16* Gb = G + (size_t)b * D * D;

    __shared__ float pv[D];
    __shared__ float partf[64][68];
    __shared__ float part2[8][68];
    __shared__ float red[8];
    __shared__ float sAlpha, sBeta, sRR;

    int t = threadIdx.x;

    float ge = 0.f;
    #pragma unroll
    for (int i = 0; i < 16; ++i) ge += psum[((size_t)b * 16 + i) * D + t];
    pv[t] = ge;
    float rel = ge, xr = 0.f;

    float rr0 = block_reduce(ge * ge, red, 8);
    if (t == 0) sRR = rr0;
    __syncthreads();
    float rr = sRR;

    int ecol = (t & 7) * 8;                   // e-octet within slice
    int cg8 = t >> 3;                         // 64 groups x 8 c
    const _Float16* gp = Gb + (size_t)(cg8 * 8) * D + sl * SW + ecol;

    for (int it = 0; it < NITER; ++it) {
        int parity = it & 1;
        float* yb = ybuf + ((size_t)b * 2 + parity) * D;
        float* pyb = pybuf + (b * 2 + parity) * SLICES;

        // partial matvec over this block's 64-col slice
        float acc[8] = {0.f, 0.f, 0.f, 0.f, 0.f, 0.f, 0.f, 0.f};
        #pragma unroll
        for (int c = 0; c < 8; ++c) {
            float pc = pv[cg8 * 8 + c];
            h16x8 q = *(const h16x8*)(gp + (size_t)c * D);
            #pragma unroll
            for (int k = 0; k < 8; ++k)
                acc[k] = fmaf((float)q[k], pc, acc[k]);
        }
        #pragma unroll
        for (int k = 0; k < 8; ++k) partf[cg8][ecol + k] = acc[k];
        __syncthreads();
        {
            int e = t & 63, g8 = t >> 6;
            float s1 = 0.f;
            #pragma unroll
            for (int k = 0; k < 8; ++k) s1 += partf[g8 * 8 + k][e];
            part2[g8][e] = s1;
        }
        __syncthreads();
        if (t < 64) {
            float y = pv[sl * SW + t];        // + I p on owned slice
            #pragma unroll
            for (int g = 0; g < 8; ++g) y += part2[g][t];
            __hip_atomic_store(&yb[sl * SW + t], y, __ATOMIC_RELEASE,
                               __HIP_MEMORY_SCOPE_AGENT);
            float pd = pv[sl * SW + t] * y;   // local p.y partial
            #pragma unroll
            for (int o = 32; o > 0; o >>= 1) pd += __shfl_down(pd, o);
            if (t == 0)
                __hip_atomic_store(&pyb[sl], pd, __ATOMIC_RELEASE,
                                   __HIP_MEMORY_SCOPE_AGENT);
        }
        __syncthreads();
        if (t == 0) {
            __threadfence();
            atomicAdd(&cnt[b], 1);
            int target = SLICES * (it + 1);
            while (__hip_atomic_load(&cnt[b], __ATOMIC_ACQUIRE,
                                     __HIP_MEMORY_SCOPE_AGENT) < target)
                __builtin_amdgcn_s_sleep(2);
        }
        __syncthreads();

        float yt = __hip_atomic_load(&yb[t], __ATOMIC_RELAXED,
                                     __HIP_MEMORY_SCOPE_AGENT);
        if (t == 0) {
            float py = 0.f;
            #pragma unroll
            for (int q2 = 0; q2 < SLICES; ++q2)
                py += __hip_atomic_load(&pyb[q2], __ATOMIC_RELAXED,
                                        __HIP_MEMORY_SCOPE_AGENT);
            sAlpha = rr / fmaxf(py, 1e-30f);
        }
        __syncthreads();
        float alpha = sAlpha;
        xr += alpha * pv[t];
        if (it + 1 == NITER) break;

        rel -= alpha * yt;
        float rrn = block_reduce(rel * rel, red, 8);
        if (t == 0) { sBeta = rrn / fmaxf(rr, 1e-30f); sRR = rrn; }
        __syncthreads();
        float beta = sBeta;
        rr = sRR;
        pv[t] = rel + beta * pv[t];
        __syncthreads();
    }

    if (sl == 0) pooled[(size_t)b * D + t] = xr;
}

// ---------------------------------------------------------------- outproj stage 1: proj = pooled @ W (e-tiled), sq partials
__global__ __launch_bounds__(256) void outproj1_kernel(const float* __restrict__ pooled,
                                                       const float* __restrict__ W,
                                                       float* __restrict__ proj,
                                                       float* __restrict__ sqpart) {
    int b = blockIdx.x, et = blockIdx.y;
    int t = threadIdx.x;
    int e = et * 64 + (t & 63);
    int dseg = t >> 6;
    __shared__ float pl[D];
    __shared__ float part[4][64];
    if (t < D / 2) {
        pl[t * 2]     = pooled[b * D + t * 2];
        pl[t * 2 + 1] = pooled[b * D + t * 2 + 1];
    }
    __syncthreads();
    float acc = 0.f;
    #pragma unroll 8
    for (int k = 0; k < 128; ++k)
        acc = fmaf(pl[dseg * 128 + k], W[(size_t)(dseg * 128 + k) * EMB + e], acc);
    part[dseg][t & 63] = acc;
    __syncthreads();
    if (t < 64) {
        float y = part[0][t] + part[1][t] + part[2][t] + part[3][t];
        proj[(size_t)b * EMB + et * 64 + t] = y;
        float sq = y * y;
        #pragma unroll
        for (int o = 32; o > 0; o >>= 1) sq += __shfl_down(sq, o);
        if (t == 0) sqpart[b * 8 + et] = sq;
    }
}

// ---------------------------------------------------------------- outproj stage 2: normalize
__global__ __launch_bounds__(512) void outproj2_kernel(const float* __restrict__ proj,
                                                       const float* __restrict__ sqpart,
                                                       float* __restrict__ out) {
    int b = blockIdx.x, t = threadIdx.x;
    float ss = 0.f;
    #pragma unroll
    for (int i = 0; i < 8; ++i) ss += sqpart[b * 8 + i];
    float s = rsqrtf(fmaxf(ss, 1e-12f));
    out[(size_t)b * EMB + t] = proj[(size_t)b * EMB + t] * s;
}

// ---------------------------------------------------------------- launch
extern "C" void kernel_launch(void* const* d_in, const int* in_sizes, int n_in,
                              void* d_out, int out_size, void* d_ws, size_t ws_size,
                              hipStream_t stream) {
    const float* x = (const float*)d_in[0];
    const float* W = (const float*)d_in[1];
    float* out = (float*)d_out;

    char* ws = (char*)d_ws;
    _Float16* G = (_Float16*)ws;                                   // 16 MB
    size_t off = (size_t)B * D * D * sizeof(_Float16);
    float* psum   = (float*)(ws + off); off += (size_t)B * 16 * D * sizeof(float);
    float* pooled = (float*)(ws + off); off += (size_t)B * D * sizeof(float);
    float* proj   = (float*)(ws + off); off += (size_t)B * EMB * sizeof(float);
    float* sqpart = (float*)(ws + off); off += (size_t)B * 8 * sizeof(float);
    float* ybuf   = (float*)(ws + off); off += (size_t)B * 2 * D * sizeof(float);
    float* pybuf  = (float*)(ws + off); off += (size_t)B * 2 * SLICES * sizeof(float);
    int*   cnt    = (int*)(ws + off);   off += (size_t)B * sizeof(int);
    off = (off + 255) & ~(size_t)255;

    size_t per_batch_q = (size_t)D * NPTS * sizeof(short);         // 1 MB fp16
    size_t avail = ws_size > off ? ws_size - off : 0;
    int CH = (int)(avail / per_batch_q);
    if (CH > B) CH = B;
    if (CH < 1) CH = 1;
    short* Qh = (short*)(ws + off);

    hipMemsetAsync(cnt, 0, (size_t)B * sizeof(int), stream);

    for (int c0 = 0; c0 < B; c0 += CH) {
        int nb = (B - c0 < CH) ? (B - c0) : CH;
        prep_kernel<<<dim3(16, 8, nb), 256, 0, stream>>>(x + (size_t)c0 * NPTS * D,
                                                         Qh, psum, c0);
        syrk_kernel<<<dim3(10, nb), 256, 0, stream>>>(Qh, G + (size_t)c0 * D * D);
    }
    cg_split_kernel<<<dim3(B * SLICES), 512, 0, stream>>>(G, psum, pooled,
                                                          ybuf, pybuf, cnt);
    outproj1_kernel<<<dim3(B, 8), 256, 0, stream>>>(pooled, W, proj, sqpart);
    outproj2_kernel<<<dim3(B), 512, 0, stream>>>(proj, sqpart, out);
}

// Round 10
// 172.682 us; speedup vs baseline: 1.8124x; 1.8124x over previous
//
#include <hip/hip_runtime.h>
#include <math.h>
#include <stdint.h>

// x (32,32,32,512) fp32, W (512,512) fp32. b=32, n=1024, d=512, emb=512, lambda=1.
// pooled = (P^T P + I)^-1 (P^T 1)  [push-through identity]
// Round 10: revert split-CG (cross-XCD sync = 17us/iter, 3x the whole iter).
// Single-block cg restructured for fixed-overhead: one triple-dot reduce per
// iter (p.y, r.y, y.y) + beta recurrence rr' = rr - 2a(r.y) + a^2(y.y);
// pair-split matvec (shfl_xor combine) halves partf and the y-gather.
// NITER 13 (anchor: 2.38e-3 < 3.30e-3). prep/syrk/outproj = round 8.

#define B    32
#define NPTS 1024
#define D    512
#define EMB  512
#define NITER 13

typedef __attribute__((ext_vector_type(8))) short short8;
typedef __attribute__((ext_vector_type(4))) float f32x4;
typedef __attribute__((ext_vector_type(8))) _Float16 h16x8;
typedef __attribute__((ext_vector_type(4))) _Float16 h16x4;

#define MFMA16F(a, b, c) __builtin_amdgcn_mfma_f32_16x16x32_f16(a, b, c, 0, 0, 0)

__device__ __forceinline__ void gload16(const void* g, void* lds_wave_base) {
    __builtin_amdgcn_global_load_lds(
        (const __attribute__((address_space(1))) void*)g,
        (__attribute__((address_space(3))) void*)lds_wave_base, 16, 0, 0);
}

// ---------------------------------------------------------------- prep: x(b,n,d) -> Q (b,d,n) fp16 + colsum partials
__global__ __launch_bounds__(256) void prep_kernel(const float* __restrict__ x,
                                                   short* __restrict__ Qh,
                                                   float* __restrict__ psum,
                                                   int b0) {
    int n0 = blockIdx.x * 64, d0 = blockIdx.y * 64, bl = blockIdx.z;
    const float* xb = x + (size_t)bl * NPTS * D;
    __shared__ float tile[64][65];
    __shared__ float cs[4][64];
    int t = threadIdx.x;
    int lrow = t >> 4, lc4 = (t & 15) * 4;
    #pragma unroll
    for (int r = 0; r < 4; ++r) {
        int row = lrow + r * 16;
        const float* src = xb + (size_t)(n0 + row) * D + d0 + lc4;
        tile[row][lc4 + 0] = src[0];
        tile[row][lc4 + 1] = src[1];
        tile[row][lc4 + 2] = src[2];
        tile[row][lc4 + 3] = src[3];
    }
    __syncthreads();

    {   // column partial sums (colsum fusion)
        int col = t & 63, grp = t >> 6;
        float s = 0.f;
        #pragma unroll
        for (int r = 0; r < 16; ++r) s += tile[grp * 16 + r][col];
        cs[grp][col] = s;
    }
    __syncthreads();
    if (t < 64)
        psum[((size_t)(b0 + bl) * 16 + blockIdx.x) * D + d0 + t] =
            cs[0][t] + cs[1][t] + cs[2][t] + cs[3][t];

    // transposed fp16 pack
    int drow = t >> 2, nseg = (t & 3) * 16;
    size_t obase = (size_t)bl * D * NPTS + (size_t)(d0 + drow) * NPTS + n0 + nseg;
    short8 h0, h1;
    #pragma unroll
    for (int k = 0; k < 8; ++k) {
        _Float16 hv = (_Float16)tile[nseg + k][drow];
        h0[k] = __builtin_bit_cast(short, hv);
    }
    #pragma unroll
    for (int k = 0; k < 8; ++k) {
        _Float16 hv = (_Float16)tile[nseg + 8 + k][drow];
        h1[k] = __builtin_bit_cast(short, hv);
    }
    *(short8*)(Qh + obase)     = h0;
    *(short8*)(Qh + obase + 8) = h1;
}

// ---------------------------------------------------------------- syrk: G = Q Q^T (fp16 MFMA), BK=64, XOR-swizzled LDS
__global__ __launch_bounds__(256) void syrk_kernel(const short* __restrict__ Qh,
                                                   _Float16* __restrict__ G) {
    int bx = blockIdx.x, bl = blockIdx.y;
    int i = 0, rem = bx;
    #pragma unroll
    for (int ii = 0; ii < 4; ++ii) {
        int c = 4 - ii;
        if (rem < c) { i = ii; break; }
        rem -= c;
    }
    int j = i + rem;
    int i0 = i * 128, j0 = j * 128;

    const short* Qhb = Qh + (size_t)bl * D * NPTS;
    _Float16* Gb = G + (size_t)bl * D * D;

    __shared__ short smem[2 * 128 * 64];   // A, B: [128][64] fp16 (16 KB each)
    char* smb = (char*)smem;

    int t = threadIdx.x;
    int lane = t & 63, wid = t >> 6;
    int wm = wid >> 1, wn = wid & 1;
    int mrow = lane & 15;
    int kq = lane >> 4;

    f32x4 acc[4][4];
    f32x4 zero = {0.f, 0.f, 0.f, 0.f};
    #pragma unroll
    for (int a = 0; a < 4; ++a)
        #pragma unroll
        for (int c = 0; c < 4; ++c) acc[a][c] = zero;

    for (int kt = 0; kt < NPTS / 64; ++kt) {
        int ks = kt * 64;
        #pragma unroll
        for (int p = 0; p < 4; ++p) {
            int off = p * 4096 + t * 16;            // linear byte offset in 16KB tile
            int row = off >> 7, inb = off & 127;
            int sinb = inb ^ ((row & 7) << 4);      // pre-swizzled global source
            int ldsoff = p * 4096 + wid * 1024;     // wave-uniform linear dest
            const char* sA = (const char*)(Qhb + (size_t)(i0 + row) * NPTS + ks) + sinb;
            const char* sB = (const char*)(Qhb + (size_t)(j0 + row) * NPTS + ks) + sinb;
            gload16(sA, smb + ldsoff);
            gload16(sB, smb + 16384 + ldsoff);
        }
        __syncthreads();

        short8 ah[2][4], bh[2][4];
        #pragma unroll
        for (int h = 0; h < 2; ++h)
            #pragma unroll
            for (int f = 0; f < 4; ++f) {
                int ra = wm * 64 + f * 16 + mrow;
                int rb = wn * 64 + f * 16 + mrow;
                int ca = (h * 4 + kq) ^ (ra & 7);
                int cb = (h * 4 + kq) ^ (rb & 7);
                ah[h][f] = *(const short8*)(smb + ra * 128 + ca * 16);
                bh[h][f] = *(const short8*)(smb + 16384 + rb * 128 + cb * 16);
            }
        #pragma unroll
        for (int h = 0; h < 2; ++h)
            #pragma unroll
            for (int fm = 0; fm < 4; ++fm)
                #pragma unroll
                for (int fn = 0; fn < 4; ++fn)
                    acc[fm][fn] = MFMA16F(__builtin_bit_cast(h16x8, ah[h][fm]),
                                          __builtin_bit_cast(h16x8, bh[h][fn]),
                                          acc[fm][fn]);
        __syncthreads();
    }

    int crow0 = i0 + wm * 64 + (lane >> 4) * 4;
    int ccol0 = j0 + wn * 64 + mrow;
    #pragma unroll
    for (int fm = 0; fm < 4; ++fm)
        #pragma unroll
        for (int fn = 0; fn < 4; ++fn)
            #pragma unroll
            for (int r = 0; r < 4; ++r)
                Gb[(size_t)(crow0 + fm * 16 + r) * D + (ccol0 + fn * 16)] =
                    (_Float16)acc[fm][fn][r];
    if (i != j) {
        #pragma unroll
        for (int fm = 0; fm < 4; ++fm)
            #pragma unroll
            for (int fn = 0; fn < 4; ++fn) {
                h16x4 v = {(_Float16)acc[fm][fn][0], (_Float16)acc[fm][fn][1],
                           (_Float16)acc[fm][fn][2], (_Float16)acc[fm][fn][3]};
                *(h16x4*)&Gb[(size_t)(ccol0 + fn * 16) * D + (crow0 + fm * 16)] = v;
            }
    }
}

// ---------------------------------------------------------------- CG solve (G+I) pooled = g, single-reduce iterations
__device__ __forceinline__ float block_reduce(float v, float* red, int nwaves) {
    #pragma unroll
    for (int o = 32; o > 0; o >>= 1) v += __shfl_down(v, o);
    int wid = threadIdx.x >> 6, lane = threadIdx.x & 63;
    __syncthreads();
    if (lane == 0) red[wid] = v;
    __syncthreads();
    float s = 0.f;
    if ((int)threadIdx.x < nwaves) {
        s = red[threadIdx.x];
        #pragma unroll
        for (int o = 8; o > 0; o >>= 1) s += __shfl_down(s, o);
    }
    return s;   // valid in thread 0
}

__global__ __launch_bounds__(1024) void cg_kernel(const _Float16* __restrict__ G,
                                                  const float* __restrict__ psum,
                                                  float* __restrict__ pooled) {
    int b = blockIdx.x;
    const _Float16* Gb = G + (size_t)b * D * D;

    __shared__ float pv[D];
    __shared__ float partf[8][512];        // 16 KB
    __shared__ float red3[3][16];
    __shared__ float red[16];
    __shared__ float sAlpha, sBeta, sRR;

    int t = threadIdx.x;
    float ge = 0.f;
    if (t < D) {
        #pragma unroll
        for (int i = 0; i < 16; ++i) ge += psum[((size_t)b * 16 + i) * D + t];
        pv[t] = ge;
    }
    float rel = ge;            // r element (t < D)
    float xr = 0.f;            // x element (t < D)

    float rr0 = block_reduce(ge * ge, red, 16);
    if (t == 0) sRR = rr0;
    __syncthreads();
    float rr = sRR;

    // matvec assignment: half = t&1, octet = (t>>1)&63, slab = t>>7
    int half = t & 1;
    int octet = (t >> 1) & 63;
    int slab = t >> 7;
    int c0 = slab * 64 + half * 32;
    const _Float16* gp = Gb + (size_t)c0 * D + octet * 8;

    for (int it = 0; it < NITER; ++it) {
        // ---- y = (G+I)p, pair-split columns
        float acc[8] = {0.f, 0.f, 0.f, 0.f, 0.f, 0.f, 0.f, 0.f};
        #pragma unroll 8
        for (int c = 0; c < 32; ++c) {
            float pc = pv[c0 + c];
            h16x8 q = *(const h16x8*)(gp + (size_t)c * D);
            #pragma unroll
            for (int k = 0; k < 8; ++k)
                acc[k] = fmaf((float)q[k], pc, acc[k]);
        }
        #pragma unroll
        for (int k = 0; k < 8; ++k) acc[k] += __shfl_xor(acc[k], 1);
        if (half == 0) {
            f32x4 a0 = {acc[0], acc[1], acc[2], acc[3]};
            f32x4 a1 = {acc[4], acc[5], acc[6], acc[7]};
            *(f32x4*)&partf[slab][octet * 8]     = a0;
            *(f32x4*)&partf[slab][octet * 8 + 4] = a1;
        }
        __syncthreads();

        // ---- gather y (register) + triple dot p.y, r.y, y.y
        float y = 0.f, pyp = 0.f, ryp = 0.f, yyp = 0.f;
        if (t < D) {
            y = pv[t];
            #pragma unroll
            for (int g = 0; g < 8; ++g) y += partf[g][t];
            pyp = pv[t] * y;
            ryp = rel * y;
            yyp = y * y;
        }
        #pragma unroll
        for (int o = 32; o > 0; o >>= 1) {
            pyp += __shfl_down(pyp, o);
            ryp += __shfl_down(ryp, o);
            yyp += __shfl_down(yyp, o);
        }
        {
            int wv = t >> 6, lane = t & 63;
            __syncthreads();
            if (lane == 0) { red3[0][wv] = pyp; red3[1][wv] = ryp; red3[2][wv] = yyp; }
            __syncthreads();
            if (t == 0) {
                float py = 0.f, ry = 0.f, yy = 0.f;
                #pragma unroll
                for (int w = 0; w < 16; ++w) {
                    py += red3[0][w]; ry += red3[1][w]; yy += red3[2][w];
                }
                float alpha = rr / fmaxf(py, 1e-30f);
                float rrn = fmaxf(rr - 2.f * alpha * ry + alpha * alpha * yy, 0.f);
                sAlpha = alpha;
                sBeta  = rrn / fmaxf(rr, 1e-30f);
                sRR    = rrn;
            }
            __syncthreads();
        }
        float alpha = sAlpha, beta = sBeta;
        rr = sRR;

        if (t < D) {
            float pold = pv[t];
            xr += alpha * pold;
            if (it + 1 < NITER) {
                rel -= alpha * y;
                pv[t] = rel + beta * pold;
            }
        }
        __syncthreads();
    }

    if (t < D) pooled[(size_t)b * D + t] = xr;
}

// ---------------------------------------------------------------- outproj stage 1: proj = pooled @ W (e-tiled), sq partials
__global__ __launch_bounds__(256) void outproj1_kernel(const float* __restrict__ pooled,
                                                       const float* __restrict__ W,
                                                       float* __restrict__ proj,
                                                       float* __restrict__ sqpart) {
    int b = blockIdx.x, et = blockIdx.y;
    int t = threadIdx.x;
    int e = et * 64 + (t & 63);
    int dseg = t >> 6;
    __shared__ float pl[D];
    __shared__ float part[4][64];
    if (t < D / 2) {
        pl[t * 2]     = pooled[b * D + t * 2];
        pl[t * 2 + 1] = pooled[b * D + t * 2 + 1];
    }
    __syncthreads();
    float acc = 0.f;
    #pragma unroll 8
    for (int k = 0; k < 128; ++k)
        acc = fmaf(pl[dseg * 128 + k], W[(size_t)(dseg * 128 + k) * EMB + e], acc);
    part[dseg][t & 63] = acc;
    __syncthreads();
    if (t < 64) {
        float y = part[0][t] + part[1][t] + part[2][t] + part[3][t];
        proj[(size_t)b * EMB + et * 64 + t] = y;
        float sq = y * y;
        #pragma unroll
        for (int o = 32; o > 0; o >>= 1) sq += __shfl_down(sq, o);
        if (t == 0) sqpart[b * 8 + et] = sq;
    }
}

// ---------------------------------------------------------------- outproj stage 2: normalize
__global__ __launch_bounds__(512) void outproj2_kernel(const float* __restrict__ proj,
                                                       const float* __restrict__ sqpart,
                                                       float* __restrict__ out) {
    int b = blockIdx.x, t = threadIdx.x;
    float ss = 0.f;
    #pragma unroll
    for (int i = 0; i < 8; ++i) ss += sqpart[b * 8 + i];
    float s = rsqrtf(fmaxf(ss, 1e-12f));
    out[(size_t)b * EMB + t] = proj[(size_t)b * EMB + t] * s;
}

// ---------------------------------------------------------------- launch
extern "C" void kernel_launch(void* const* d_in, const int* in_sizes, int n_in,
                              void* d_out, int out_size, void* d_ws, size_t ws_size,
                              hipStream_t stream) {
    const float* x = (const float*)d_in[0];
    const float* W = (const float*)d_in[1];
    float* out = (float*)d_out;

    char* ws = (char*)d_ws;
    _Float16* G = (_Float16*)ws;                                   // 16 MB
    size_t off = (size_t)B * D * D * sizeof(_Float16);
    float* psum   = (float*)(ws + off); off += (size_t)B * 16 * D * sizeof(float);
    float* pooled = (float*)(ws + off); off += (size_t)B * D * sizeof(float);
    float* proj   = (float*)(ws + off); off += (size_t)B * EMB * sizeof(float);
    float* sqpart = (float*)(ws + off); off += (size_t)B * 8 * sizeof(float);
    off = (off + 255) & ~(size_t)255;

    size_t per_batch_q = (size_t)D * NPTS * sizeof(short);         // 1 MB fp16
    size_t avail = ws_size > off ? ws_size - off : 0;
    int CH = (int)(avail / per_batch_q);
    if (CH > B) CH = B;
    if (CH < 1) CH = 1;
    short* Qh = (short*)(ws + off);

    for (int c0 = 0; c0 < B; c0 += CH) {
        int nb = (B - c0 < CH) ? (B - c0) : CH;
        prep_kernel<<<dim3(16, 8, nb), 256, 0, stream>>>(x + (size_t)c0 * NPTS * D,
                                                         Qh, psum, c0);
        syrk_kernel<<<dim3(10, nb), 256, 0, stream>>>(Qh, G + (size_t)c0 * D * D);
    }
    cg_kernel<<<dim3(B), 1024, 0, stream>>>(G, psum, pooled);
    outproj1_kernel<<<dim3(B, 8), 256, 0, stream>>>(pooled, W, proj, sqpart);
    outproj2_kernel<<<dim3(B), 512, 0, stream>>>(proj, sqpart, out);
}